// Round 6
// baseline (1318.562 us; speedup 1.0000x reference)
//
#include <hip/hip_runtime.h>
#include <stdint.h>

#define NPTS 4096
#define KREG 1024
#define NS   64
#define NB   16
#define PTOT (NB*KREG*NS)        // 1048576 positions
#define NWAVE (PTOT/64)          // 16384
#define GATH_BLOCKS 256

// ---------------------------------------------------------------------------
// Wave-wide u64 max, ALL-VALU: DPP strides 1/2/4/8 (quad_perm+mirrors) then
// row_bcast15 / row_bcast31. Max-fold is immune to bound_ctrl zeros (keys
// are non-negative). Lane 63 ends up holding the wave-wide max.
// ---------------------------------------------------------------------------
__device__ __forceinline__ unsigned long long wave_max_u64_dpp(unsigned long long k)
{
#define STEP_DPP(ctrl) { \
    unsigned lo = (unsigned)k, hi = (unsigned)(k >> 32); \
    unsigned olo = (unsigned)__builtin_amdgcn_mov_dpp((int)lo, ctrl, 0xF, 0xF, true); \
    unsigned ohi = (unsigned)__builtin_amdgcn_mov_dpp((int)hi, ctrl, 0xF, 0xF, true); \
    unsigned long long o = ((unsigned long long)ohi << 32) | olo; \
    if (o > k) k = o; }
    STEP_DPP(0xB1)    // quad_perm xor1
    STEP_DPP(0x4E)    // quad_perm xor2
    STEP_DPP(0x141)   // row_half_mirror
    STEP_DPP(0x140)   // row_mirror -> each 16-lane row has its max everywhere
    STEP_DPP(0x142)   // row_bcast15: rows 1..3 fold in previous row's max
    STEP_DPP(0x143)   // row_bcast31: lanes 32-63 fold in max(rows 0-1)
#undef STEP_DPP
    return k;         // valid in lane 63
}

// ---------------------------------------------------------------------------
// FPS: one block per batch, 512 threads (8 waves), 8 points/thread in
// REGISTERS. Exact f32 (no FMA) to match numpy. Per-thread best tracked as
// (f32 dist, u32 low) with first-j-wins compare (== min index on ties);
// u64 key built once per iteration. Wave reduce is all-VALU DPP; lane 63
// writes the wave key to a parity-slot LDS array; one barrier; all threads
// combine 8 keys via 4 independent ds_read_b128. Centroids buffered in the
// free .w words of pcL (no per-iter global store -> no vmcnt drain at the
// barrier), flushed coalesced at the end.
// ---------------------------------------------------------------------------
__global__ __launch_bounds__(512) void fps_kernel(
    const float* __restrict__ pc, float* __restrict__ outC)
{
    __shared__ float4 pcL[NPTS];                     // 64 KB; .w = centroid buf
    __shared__ alignas(16) unsigned long long wpart[2][8];

    const int b = blockIdx.x;
    const int t = threadIdx.x;
    const int wv = t >> 6;
    const float* px = pc + (size_t)b * 3 * NPTS;

    float lx[8], ly[8], lz[8], md[8];
    #pragma unroll
    for (int j = 0; j < 8; ++j) {
        int p = j * 512 + t;
        float x = px[p], y = px[NPTS + p], z = px[2 * NPTS + p];
        lx[j] = x; ly[j] = y; lz[j] = z;
        pcL[p] = make_float4(x, y, z, 0.0f);
        md[j] = 1e10f;
    }
    __syncthreads();
    float4 cc = pcL[0];
    const unsigned cbase = 0xFFFFFFFFu - (unsigned)t;

    for (int it = 0; it < KREG; ++it) {
        // stash this iteration's centroid into the free .w words (LDS only)
        if (t == 0) {
            pcL[it].w        = cc.x;
            pcL[1024 + it].w = cc.y;
            pcL[2048 + it].w = cc.z;
        }
        float mbest = -1.0f;
        unsigned lowbest = 0u;
        #pragma unroll
        for (int j = 0; j < 8; ++j) {
            float dx = __fsub_rn(lx[j], cc.x);
            float dy = __fsub_rn(ly[j], cc.y);
            float dz = __fsub_rn(lz[j], cc.z);
            float d = __fadd_rn(__fadd_rn(__fmul_rn(dx, dx), __fmul_rn(dy, dy)),
                                __fmul_rn(dz, dz));
            float m = fminf(md[j], d);
            md[j] = m;
            if (m > mbest) {              // strict > : first j wins ties
                mbest = m;
                lowbest = cbase - (unsigned)(j * 512);   // = ~p, p = j*512+t
            }
        }
        unsigned long long best =
            ((unsigned long long)__float_as_uint(mbest) << 32) |
            (unsigned long long)lowbest;

        unsigned long long kmax = wave_max_u64_dpp(best);
        if ((t & 63) == 63) wpart[it & 1][wv] = kmax;
        __syncthreads();
        const unsigned long long* wp = &wpart[it & 1][0];
        ulonglong2 k01 = *(const ulonglong2*)&wp[0];
        ulonglong2 k23 = *(const ulonglong2*)&wp[2];
        ulonglong2 k45 = *(const ulonglong2*)&wp[4];
        ulonglong2 k67 = *(const ulonglong2*)&wp[6];
        unsigned long long ka = (k01.x > k01.y) ? k01.x : k01.y;
        unsigned long long kb = (k23.x > k23.y) ? k23.x : k23.y;
        unsigned long long kc = (k45.x > k45.y) ? k45.x : k45.y;
        unsigned long long kd = (k67.x > k67.y) ? k67.x : k67.y;
        unsigned long long ke = (ka > kb) ? ka : kb;
        unsigned long long kf = (kc > kd) ? kc : kd;
        unsigned long long kk = (ke > kf) ? ke : kf;
        int f = (int)(0xFFFFFFFFu - (unsigned)kk);
        cc = pcL[f];                      // broadcast read; .w ignored
    }
    __syncthreads();
    // flush centroids: coalesced within each coordinate plane
    for (int i = t; i < KREG; i += 512) {
        outC[(size_t)b * 3 * KREG + i]            = pcL[i].w;
        outC[(size_t)b * 3 * KREG + KREG + i]     = pcL[1024 + i].w;
        outC[(size_t)b * 3 * KREG + 2 * KREG + i] = pcL[2048 + i].w;
    }
}

// ---------------------------------------------------------------------------
// Ball query: one wave per centroid. Exact f32 (c2+x2)-2*dot formula.
// Keeps first NS in-radius indices in ascending order; pads with first index.
// ---------------------------------------------------------------------------
__global__ __launch_bounds__(256) void ballquery_kernel(
    const float* __restrict__ pc, const float* __restrict__ outC,
    int* __restrict__ gidx)
{
    int gw = blockIdx.x * 4 + (threadIdx.x >> 6);
    int lane = threadIdx.x & 63;
    int b = gw >> 10;
    int k = gw & (KREG - 1);
    const float* px = pc + (size_t)b * 3 * NPTS;

    float cx = outC[(size_t)b * 3 * KREG + k];
    float cy = outC[(size_t)b * 3 * KREG + KREG + k];
    float cz = outC[(size_t)b * 3 * KREG + 2 * KREG + k];
    float c2 = __fadd_rn(__fadd_rn(__fmul_rn(cx, cx), __fmul_rn(cy, cy)),
                         __fmul_rn(cz, cz));
    const float r2 = 0.16f;
    int base = gw * NS;
    int cnt = 0;
    int firstidx = -1;

    for (int nb = 0; nb < NPTS / 64; ++nb) {
        int n = nb * 64 + lane;
        float x = px[n], y = px[NPTS + n], z = px[2 * NPTS + n];
        float x2 = __fadd_rn(__fadd_rn(__fmul_rn(x, x), __fmul_rn(y, y)),
                             __fmul_rn(z, z));
        float dt = __fadd_rn(__fadd_rn(__fmul_rn(cx, x), __fmul_rn(cy, y)),
                             __fmul_rn(cz, z));
        float sqd = __fsub_rn(__fadd_rn(c2, x2), __fmul_rn(2.0f, dt));
        bool pred = (sqd <= r2);
        unsigned long long mask = __ballot(pred);
        if (firstidx < 0 && mask) firstidx = nb * 64 + __ffsll((long long)mask) - 1;
        int pos = cnt + __popcll(mask & ((1ull << lane) - 1ull));
        if (pred && pos < NS) gidx[base + pos] = n;
        cnt += __popcll(mask);
        if (cnt >= NS) break;
    }
    if (lane >= cnt) gidx[base + lane] = firstidx;
}

// ---------------------------------------------------------------------------
// Gather grouped coords (planar (3,P)) + 3x3 second-moment partials for BN1.
// ---------------------------------------------------------------------------
__global__ __launch_bounds__(256) void gather_kernel(
    const float* __restrict__ pc, const float* __restrict__ outC,
    const int* __restrict__ gidx, float* __restrict__ X0,
    float* __restrict__ mpart)
{
    float a[9] = {0, 0, 0, 0, 0, 0, 0, 0, 0};
    for (int p = blockIdx.x * 256 + threadIdx.x; p < PTOT; p += GATH_BLOCKS * 256) {
        int bk = p >> 6;
        int b = bk >> 10;
        int k = bk & (KREG - 1);
        int idx = gidx[p];
        const float* px = pc + (size_t)b * 3 * NPTS;
        float x = px[idx]            - outC[(size_t)b * 3 * KREG + k];
        float y = px[NPTS + idx]     - outC[(size_t)b * 3 * KREG + KREG + k];
        float z = px[2 * NPTS + idx] - outC[(size_t)b * 3 * KREG + 2 * KREG + k];
        X0[p] = x; X0[PTOT + p] = y; X0[2 * PTOT + p] = z;
        a[0] += x;     a[1] += y;     a[2] += z;
        a[3] += x * x; a[4] += y * y; a[5] += z * z;
        a[6] += x * y; a[7] += x * z; a[8] += y * z;
    }
    __shared__ float red[4][9];
    int wv = threadIdx.x >> 6;
    #pragma unroll
    for (int q = 0; q < 9; ++q) {
        float v = a[q];
        #pragma unroll
        for (int s = 32; s > 0; s >>= 1) v += __shfl_xor(v, s, 64);
        if ((threadIdx.x & 63) == 0) red[wv][q] = v;
    }
    __syncthreads();
    if (threadIdx.x < 9) {
        mpart[blockIdx.x * 9 + threadIdx.x] =
            red[0][threadIdx.x] + red[1][threadIdx.x] +
            red[2][threadIdx.x] + red[3][threadIdx.x];
    }
}

// ---------------------------------------------------------------------------
// BN1 params analytically from moments: y1 = W1 x + b1 is linear in x.
// ---------------------------------------------------------------------------
__global__ void bn1_finalize(
    const float* __restrict__ mpart, const float* __restrict__ w1,
    const float* __restrict__ b1, const float* __restrict__ g1,
    const float* __restrict__ be1, float* __restrict__ sc1,
    float* __restrict__ sh1)
{
    __shared__ double M[9];
    int t = threadIdx.x;
    if (t < 9) {
        double s = 0;
        for (int i = 0; i < GATH_BLOCKS; ++i) s += (double)mpart[i * 9 + t];
        M[t] = s / (double)PTOT;
    }
    __syncthreads();
    if (t < 64) {
        double mux = M[0], muy = M[1], muz = M[2];
        double xx = M[3], yy = M[4], zz = M[5], xy = M[6], xz = M[7], yz = M[8];
        double wx = w1[t * 3], wy = w1[t * 3 + 1], wz = w1[t * 3 + 2], bb = b1[t];
        double wmu = wx * mux + wy * muy + wz * muz;
        double mean = wmu + bb;
        double ey2 = wx * wx * xx + wy * wy * yy + wz * wz * zz
                   + 2.0 * (wx * wy * xy + wx * wz * xz + wy * wz * yz)
                   + 2.0 * bb * wmu + bb * bb;
        double var = ey2 - mean * mean;
        double scale = (double)g1[t] / sqrt(var + 1e-5);
        sc1[t] = (float)scale;
        sh1[t] = (float)((double)be1[t] - mean * scale);
    }
}

// ---------------------------------------------------------------------------
// Transpose small weight matrices so conv loops read contiguous (-> s_load).
// ---------------------------------------------------------------------------
__global__ __launch_bounds__(256) void prep_kernel(
    const float* __restrict__ w2, const float* __restrict__ w3,
    float* __restrict__ w2t, float* __restrict__ w3t)
{
    int t = blockIdx.x * 256 + threadIdx.x;
    if (t < 4096) w2t[(t & 63) * 64 + (t >> 6)] = w2[t];
    if (t < 8192) w3t[(t & 63) * 128 + (t >> 6)] = w3[t];
}

// ---------------------------------------------------------------------------
// Pass A: conv1+BN1+ReLU -> conv2, accumulate per-channel sum/sumsq of y2.
// 128 threads/block, 1 position/thread. Activations in LDS columns.
// ---------------------------------------------------------------------------
__global__ __launch_bounds__(128) void conv12_stats_kernel(
    const float* __restrict__ X0,
    const float* __restrict__ w1, const float* __restrict__ b1,
    const float* __restrict__ sc1, const float* __restrict__ sh1,
    const float* __restrict__ w2t, const float* __restrict__ b2,
    float* __restrict__ sum2, float* __restrict__ sq2)
{
    __shared__ float xbuf[64 * 128];
    __shared__ float trans[2][8][65];
    const int t = threadIdx.x;
    const int p = blockIdx.x * 128 + t;

    float x = X0[p], y = X0[PTOT + p], z = X0[2 * PTOT + p];
    #pragma unroll
    for (int o = 0; o < 64; ++o) {
        float v = b1[o];
        v = fmaf(w1[o * 3 + 2], z, v);
        v = fmaf(w1[o * 3 + 1], y, v);
        v = fmaf(w1[o * 3 + 0], x, v);
        v = fmaf(v, sc1[o], sh1[o]);
        xbuf[o * 128 + t] = fmaxf(v, 0.0f);
    }
    float acc[64];
    #pragma unroll
    for (int o = 0; o < 64; ++o) acc[o] = b2[o];
    for (int c = 0; c < 64; ++c) {
        float xv = xbuf[c * 128 + t];
        #pragma unroll
        for (int o = 0; o < 64; ++o) acc[o] = fmaf(w2t[c * 64 + o], xv, acc[o]);
    }
    const int wv = t >> 6, lane = t & 63;
    const int gw = blockIdx.x * 2 + wv;
    #pragma unroll
    for (int ch = 0; ch < 8; ++ch) {
        __syncthreads();
        #pragma unroll
        for (int o = 0; o < 8; ++o) trans[wv][o][lane] = acc[ch * 8 + o];
        __syncthreads();
        int row = lane >> 3, seg = lane & 7;
        float s = 0.f, q = 0.f;
        #pragma unroll
        for (int j = 0; j < 8; ++j) {
            float v = trans[wv][row][seg * 8 + j];
            s += v; q = fmaf(v, v, q);
        }
        s += __shfl_xor(s, 1, 64); q += __shfl_xor(q, 1, 64);
        s += __shfl_xor(s, 2, 64); q += __shfl_xor(q, 2, 64);
        s += __shfl_xor(s, 4, 64); q += __shfl_xor(q, 4, 64);
        if (seg == 0) {
            int o = ch * 8 + row;
            sum2[(size_t)o * NWAVE + gw] = s;
            sq2[(size_t)o * NWAVE + gw] = q;
        }
    }
}

// ---------------------------------------------------------------------------
// Generic BN finalize: per-channel block sums wave partials (f64), emits
// scale/shift.
// ---------------------------------------------------------------------------
__global__ __launch_bounds__(256) void bn_finalize_kernel(
    const float* __restrict__ sumb, const float* __restrict__ sqb,
    const float* __restrict__ g, const float* __restrict__ be,
    float* __restrict__ sc, float* __restrict__ sh)
{
    int o = blockIdx.x, t = threadIdx.x;
    double s = 0, q = 0;
    for (int i = t; i < NWAVE; i += 256) {
        s += (double)sumb[(size_t)o * NWAVE + i];
        q += (double)sqb[(size_t)o * NWAVE + i];
    }
    #pragma unroll
    for (int m = 32; m > 0; m >>= 1) {
        s += __shfl_xor(s, m, 64);
        q += __shfl_xor(q, m, 64);
    }
    __shared__ double rs[4], rq[4];
    if ((t & 63) == 0) { rs[t >> 6] = s; rq[t >> 6] = q; }
    __syncthreads();
    if (t == 0) {
        s = rs[0] + rs[1] + rs[2] + rs[3];
        q = rq[0] + rq[1] + rq[2] + rq[3];
        double mean = s / (double)PTOT;
        double var = q / (double)PTOT - mean * mean;
        double scale = (double)g[o] / sqrt(var + 1e-5);
        sc[o] = (float)scale;
        sh[o] = (float)((double)be[o] - mean * scale);
    }
}

// ---------------------------------------------------------------------------
// Pass B: recompute conv1->conv2 (BN params now known), conv3; emit per-(bk,o)
// max/min of y3 plus per-channel sum/sumsq partials. y3 never stored.
// ---------------------------------------------------------------------------
__global__ __launch_bounds__(128) void conv123_kernel(
    const float* __restrict__ X0,
    const float* __restrict__ w1, const float* __restrict__ b1,
    const float* __restrict__ sc1, const float* __restrict__ sh1,
    const float* __restrict__ w2t, const float* __restrict__ b2,
    const float* __restrict__ sc2, const float* __restrict__ sh2,
    const float* __restrict__ w3t, const float* __restrict__ b3,
    float* __restrict__ y3max, float* __restrict__ y3min,
    float* __restrict__ sum3, float* __restrict__ sq3)
{
    __shared__ float xbuf[64 * 128];
    __shared__ float trans[2][8][65];
    const int t = threadIdx.x;
    const int p = blockIdx.x * 128 + t;

    float x = X0[p], y = X0[PTOT + p], z = X0[2 * PTOT + p];
    #pragma unroll
    for (int o = 0; o < 64; ++o) {
        float v = b1[o];
        v = fmaf(w1[o * 3 + 2], z, v);
        v = fmaf(w1[o * 3 + 1], y, v);
        v = fmaf(w1[o * 3 + 0], x, v);
        v = fmaf(v, sc1[o], sh1[o]);
        xbuf[o * 128 + t] = fmaxf(v, 0.0f);
    }
    float acc2[64];
    #pragma unroll
    for (int o = 0; o < 64; ++o) acc2[o] = b2[o];
    for (int c = 0; c < 64; ++c) {
        float xv = xbuf[c * 128 + t];
        #pragma unroll
        for (int o = 0; o < 64; ++o) acc2[o] = fmaf(w2t[c * 64 + o], xv, acc2[o]);
    }
    #pragma unroll
    for (int o = 0; o < 64; ++o) {
        xbuf[o * 128 + t] = fmaxf(fmaf(acc2[o], sc2[o], sh2[o]), 0.0f);
    }
    float acc3[128];
    #pragma unroll
    for (int o = 0; o < 128; ++o) acc3[o] = b3[o];
    for (int c = 0; c < 64; ++c) {
        float xv = xbuf[c * 128 + t];
        #pragma unroll
        for (int o = 0; o < 128; ++o) acc3[o] = fmaf(w3t[c * 128 + o], xv, acc3[o]);
    }
    const int wv = t >> 6, lane = t & 63;
    const int gw = blockIdx.x * 2 + wv;   // == bk (group) index
    #pragma unroll
    for (int ch = 0; ch < 16; ++ch) {
        __syncthreads();
        #pragma unroll
        for (int o = 0; o < 8; ++o) trans[wv][o][lane] = acc3[ch * 8 + o];
        __syncthreads();
        int row = lane >> 3, seg = lane & 7;
        float s = 0.f, q = 0.f, mx = -1e30f, mn = 1e30f;
        #pragma unroll
        for (int j = 0; j < 8; ++j) {
            float v = trans[wv][row][seg * 8 + j];
            s += v; q = fmaf(v, v, q);
            mx = fmaxf(mx, v); mn = fminf(mn, v);
        }
        s += __shfl_xor(s, 1, 64); q += __shfl_xor(q, 1, 64);
        mx = fmaxf(mx, __shfl_xor(mx, 1, 64)); mn = fminf(mn, __shfl_xor(mn, 1, 64));
        s += __shfl_xor(s, 2, 64); q += __shfl_xor(q, 2, 64);
        mx = fmaxf(mx, __shfl_xor(mx, 2, 64)); mn = fminf(mn, __shfl_xor(mn, 2, 64));
        s += __shfl_xor(s, 4, 64); q += __shfl_xor(q, 4, 64);
        mx = fmaxf(mx, __shfl_xor(mx, 4, 64)); mn = fminf(mn, __shfl_xor(mn, 4, 64));
        if (seg == 0) {
            int o = ch * 8 + row;
            y3max[(size_t)gw * 128 + o] = mx;
            y3min[(size_t)gw * 128 + o] = mn;
            sum3[(size_t)o * NWAVE + gw] = s;
            sq3[(size_t)o * NWAVE + gw] = q;
        }
    }
}

// ---------------------------------------------------------------------------
// Final: feats[b,o,k] = relu(scale3*extreme + shift3), transposed via LDS.
// max over samples commutes with the monotone BN+ReLU (min if scale<0).
// ---------------------------------------------------------------------------
__global__ __launch_bounds__(256) void feats_kernel(
    const float* __restrict__ y3max, const float* __restrict__ y3min,
    const float* __restrict__ sc3, const float* __restrict__ sh3,
    float* __restrict__ feats)
{
    __shared__ float tile[64][129];
    int blk = blockIdx.x;          // b*16 + kt
    int b = blk >> 4, kt = blk & 15;
    int t = threadIdx.x;
    size_t bk0 = (size_t)(b * KREG + kt * 64);
    #pragma unroll
    for (int i = 0; i < 32; ++i) {
        int idx = i * 256 + t;
        int o = idx & 127, kk = idx >> 7;
        float a = sc3[o];
        float v = (a >= 0.f) ? y3max[(bk0 + kk) * 128 + o]
                             : y3min[(bk0 + kk) * 128 + o];
        tile[kk][o] = fmaxf(fmaf(v, a, sh3[o]), 0.0f);
    }
    __syncthreads();
    #pragma unroll
    for (int i = 0; i < 32; ++i) {
        int idx = i * 256 + t;
        int kk = idx & 63, o = idx >> 6;
        feats[(size_t)b * 128 * KREG + (size_t)o * KREG + kt * 64 + kk] = tile[kk][o];
    }
}

// ---------------------------------------------------------------------------
extern "C" void kernel_launch(void* const* d_in, const int* in_sizes, int n_in,
                              void* d_out, int out_size, void* d_ws, size_t ws_size,
                              hipStream_t stream)
{
    const float* pc  = (const float*)d_in[0];
    const float* w1  = (const float*)d_in[1];
    const float* b1  = (const float*)d_in[2];
    const float* g1  = (const float*)d_in[3];
    const float* be1 = (const float*)d_in[4];
    const float* w2  = (const float*)d_in[5];
    const float* b2  = (const float*)d_in[6];
    const float* g2  = (const float*)d_in[7];
    const float* be2 = (const float*)d_in[8];
    const float* w3  = (const float*)d_in[9];
    const float* b3  = (const float*)d_in[10];
    const float* g3  = (const float*)d_in[11];
    const float* be3 = (const float*)d_in[12];

    float* outC  = (float*)d_out;                      // (16,3,1024)
    float* feats = (float*)d_out + NB * 3 * KREG;      // (16,128,1024)

    const size_t MB = 1024 * 1024;
    char* ws = (char*)d_ws;
    int*   gidx  = (int*)ws;                           // 4 MB
    float* X0    = (float*)(ws + 4 * MB);              // 12 MB (3 x P)
    float* mpart = (float*)(ws + 16 * MB);             // 9216 B
    float* sc1   = (float*)(ws + 16 * MB + 16 * 1024);
    float* sh1   = (float*)(ws + 16 * MB + 17 * 1024);
    float* sc2   = (float*)(ws + 16 * MB + 18 * 1024);
    float* sh2   = (float*)(ws + 16 * MB + 19 * 1024);
    float* sc3   = (float*)(ws + 16 * MB + 20 * 1024);
    float* sh3   = (float*)(ws + 16 * MB + 21 * 1024);
    float* w2t   = (float*)(ws + 16 * MB + 32 * 1024); // 16 KB
    float* w3t   = (float*)(ws + 16 * MB + 64 * 1024); // 32 KB
    float* sum2  = (float*)(ws + 17 * MB);             // 4 MB
    float* sq2   = (float*)(ws + 21 * MB);             // 4 MB
    float* sum3  = (float*)(ws + 25 * MB);             // 8 MB
    float* sq3   = (float*)(ws + 33 * MB);             // 8 MB
    float* y3max = (float*)(ws + 41 * MB);             // 8 MB
    float* y3min = (float*)(ws + 49 * MB);             // 8 MB

    fps_kernel<<<NB, 512, 0, stream>>>(pc, outC);
    ballquery_kernel<<<(NB * KREG) / 4, 256, 0, stream>>>(pc, outC, gidx);
    gather_kernel<<<GATH_BLOCKS, 256, 0, stream>>>(pc, outC, gidx, X0, mpart);
    bn1_finalize<<<1, 64, 0, stream>>>(mpart, w1, b1, g1, be1, sc1, sh1);
    prep_kernel<<<32, 256, 0, stream>>>(w2, w3, w2t, w3t);
    conv12_stats_kernel<<<PTOT / 128, 128, 0, stream>>>(
        X0, w1, b1, sc1, sh1, w2t, b2, sum2, sq2);
    bn_finalize_kernel<<<64, 256, 0, stream>>>(sum2, sq2, g2, be2, sc2, sh2);
    conv123_kernel<<<PTOT / 128, 128, 0, stream>>>(
        X0, w1, b1, sc1, sh1, w2t, b2, sc2, sh2, w3t, b3,
        y3max, y3min, sum3, sq3);
    bn_finalize_kernel<<<128, 256, 0, stream>>>(sum3, sq3, g3, be3, sc3, sh3);
    feats_kernel<<<NB * (KREG / 64), 256, 0, stream>>>(y3max, y3min, sc3, sh3, feats);
}

// Round 7
// 1266.197 us; speedup vs baseline: 1.0414x; 1.0414x over previous
//
#include <hip/hip_runtime.h>
#include <stdint.h>

#define NPTS 4096
#define KREG 1024
#define NS   64
#define NB   16
#define PTOT (NB*KREG*NS)        // 1048576 positions
#define NWAVE (PTOT/64)          // 16384
#define GATH_BLOCKS 256

typedef float v2f __attribute__((ext_vector_type(2)));

// ---------------------------------------------------------------------------
// FPS: one block per batch, 256 threads (4 waves, 1/SIMD), 16 CONSECUTIVE
// points per thread (p = t*16 + j). Exact f32 (contract-off packed ops ==
// IEEE rn, bit-identical to __fsub_rn/__fmul_rn/__fadd_rn chain).
// Argmax tie-break (max dist, then first index): per-thread first-j via
// strict >; per-wave min-lane via ballot+ffs (p-order == (t,j) lex order);
// per-wave key built in SGPRs; cross-wave combine via parity-slot LDS.
// Centroids buffered in free .w words of pcL; flushed at the end.
// ---------------------------------------------------------------------------
__global__ __launch_bounds__(256) void fps_kernel(
    const float* __restrict__ pc, float* __restrict__ outC)
{
#pragma clang fp contract(off)
    __shared__ float4 pcL[NPTS];                     // 64 KB; .w = centroid buf
    __shared__ alignas(16) unsigned long long wpart[2][4];

    const int b = blockIdx.x;
    const int t = threadIdx.x;
    const int wv = t >> 6;
    const int lane = t & 63;
    const float* px = pc + (size_t)b * 3 * NPTS;

    v2f lx[8], ly[8], lz[8], md[8];
    {
        const float4* px4 = (const float4*)(px + t * 16);
        const float4* py4 = (const float4*)(px + NPTS + t * 16);
        const float4* pz4 = (const float4*)(px + 2 * NPTS + t * 16);
        #pragma unroll
        for (int q = 0; q < 4; ++q) {
            float4 xx = px4[q], yy = py4[q], zz = pz4[q];
            lx[2*q]   = (v2f){xx.x, xx.y};  lx[2*q+1] = (v2f){xx.z, xx.w};
            ly[2*q]   = (v2f){yy.x, yy.y};  ly[2*q+1] = (v2f){yy.z, yy.w};
            lz[2*q]   = (v2f){zz.x, zz.y};  lz[2*q+1] = (v2f){zz.z, zz.w};
            md[2*q]   = (v2f){1e10f, 1e10f};
            md[2*q+1] = (v2f){1e10f, 1e10f};
            pcL[t*16 + 4*q + 0] = make_float4(xx.x, yy.x, zz.x, 0.f);
            pcL[t*16 + 4*q + 1] = make_float4(xx.y, yy.y, zz.y, 0.f);
            pcL[t*16 + 4*q + 2] = make_float4(xx.z, yy.z, zz.z, 0.f);
            pcL[t*16 + 4*q + 3] = make_float4(xx.w, yy.w, zz.w, 0.f);
        }
    }
    __syncthreads();
    float4 cc = pcL[0];                              // point p = 0

    for (int it = 0; it < KREG; ++it) {
        if (t == 0) {                                // LDS-only centroid stash
            pcL[it].w        = cc.x;
            pcL[1024 + it].w = cc.y;
            pcL[2048 + it].w = cc.z;
        }
        const v2f cx2 = (v2f){cc.x, cc.x};
        const v2f cy2 = (v2f){cc.y, cc.y};
        const v2f cz2 = (v2f){cc.z, cc.z};
        float mbest = -1.0f;
        int jbest = 0;
        #pragma unroll
        for (int q = 0; q < 8; ++q) {
            v2f dx = lx[q] - cx2;
            v2f dy = ly[q] - cy2;
            v2f dz = lz[q] - cz2;
            v2f d  = (dx * dx + dy * dy) + dz * dz;  // contract OFF: pure rn
            v2f m;
            m.x = fminf(md[q].x, d.x);
            m.y = fminf(md[q].y, d.y);
            md[q] = m;
            if (m.x > mbest) { mbest = m.x; jbest = 2 * q; }      // first j wins
            if (m.y > mbest) { mbest = m.y; jbest = 2 * q + 1; }
        }
        // wave max of mbest: all-VALU DPP cascade, result valid in lane 63
        float r = mbest;
#define MSTEP(ctrl) { \
        float o = __int_as_float(__builtin_amdgcn_mov_dpp( \
                      __float_as_int(r), ctrl, 0xF, 0xF, true)); \
        r = fmaxf(r, o); }
        MSTEP(0xB1) MSTEP(0x4E) MSTEP(0x141) MSTEP(0x140) MSTEP(0x142) MSTEP(0x143)
#undef MSTEP
        float mxw = __int_as_float(
            __builtin_amdgcn_readlane(__float_as_int(r), 63));
        // min-lane winner (== min p, since p = t*16+j is lex (t, j))
        unsigned long long ball = __ballot(mbest == mxw);
        int L = __ffsll((long long)ball) - 1;
        int jw = __builtin_amdgcn_readlane(jbest, L);
        unsigned pw = ((unsigned)(wv * 64 + L) << 4) + (unsigned)jw;
        unsigned long long key =
            ((unsigned long long)__float_as_uint(mxw) << 32) |
            (unsigned long long)(0xFFFFFFFFu - pw);
        if (lane == 0) wpart[it & 1][wv] = key;
        __syncthreads();
        const unsigned long long* wp = &wpart[it & 1][0];
        ulonglong2 k01 = *(const ulonglong2*)&wp[0];
        ulonglong2 k23 = *(const ulonglong2*)&wp[2];
        unsigned long long ka = (k01.x > k01.y) ? k01.x : k01.y;
        unsigned long long kb = (k23.x > k23.y) ? k23.x : k23.y;
        unsigned long long kk = (ka > kb) ? ka : kb;
        int f = (int)(0xFFFFFFFFu - (unsigned)kk);
        cc = pcL[f];                                 // broadcast; .w ignored
    }
    __syncthreads();
    for (int i = t; i < KREG; i += 256) {
        outC[(size_t)b * 3 * KREG + i]            = pcL[i].w;
        outC[(size_t)b * 3 * KREG + KREG + i]     = pcL[1024 + i].w;
        outC[(size_t)b * 3 * KREG + 2 * KREG + i] = pcL[2048 + i].w;
    }
}

// ---------------------------------------------------------------------------
// Ball query: one wave per centroid. Exact f32 (c2+x2)-2*dot formula.
// Keeps first NS in-radius indices in ascending order; pads with first index.
// ---------------------------------------------------------------------------
__global__ __launch_bounds__(256) void ballquery_kernel(
    const float* __restrict__ pc, const float* __restrict__ outC,
    int* __restrict__ gidx)
{
    int gw = blockIdx.x * 4 + (threadIdx.x >> 6);
    int lane = threadIdx.x & 63;
    int b = gw >> 10;
    int k = gw & (KREG - 1);
    const float* px = pc + (size_t)b * 3 * NPTS;

    float cx = outC[(size_t)b * 3 * KREG + k];
    float cy = outC[(size_t)b * 3 * KREG + KREG + k];
    float cz = outC[(size_t)b * 3 * KREG + 2 * KREG + k];
    float c2 = __fadd_rn(__fadd_rn(__fmul_rn(cx, cx), __fmul_rn(cy, cy)),
                         __fmul_rn(cz, cz));
    const float r2 = 0.16f;
    int base = gw * NS;
    int cnt = 0;
    int firstidx = -1;

    for (int nb = 0; nb < NPTS / 64; ++nb) {
        int n = nb * 64 + lane;
        float x = px[n], y = px[NPTS + n], z = px[2 * NPTS + n];
        float x2 = __fadd_rn(__fadd_rn(__fmul_rn(x, x), __fmul_rn(y, y)),
                             __fmul_rn(z, z));
        float dt = __fadd_rn(__fadd_rn(__fmul_rn(cx, x), __fmul_rn(cy, y)),
                             __fmul_rn(cz, z));
        float sqd = __fsub_rn(__fadd_rn(c2, x2), __fmul_rn(2.0f, dt));
        bool pred = (sqd <= r2);
        unsigned long long mask = __ballot(pred);
        if (firstidx < 0 && mask) firstidx = nb * 64 + __ffsll((long long)mask) - 1;
        int pos = cnt + __popcll(mask & ((1ull << lane) - 1ull));
        if (pred && pos < NS) gidx[base + pos] = n;
        cnt += __popcll(mask);
        if (cnt >= NS) break;
    }
    if (lane >= cnt) gidx[base + lane] = firstidx;
}

// ---------------------------------------------------------------------------
// Gather grouped coords (planar (3,P)) + 3x3 second-moment partials for BN1.
// ---------------------------------------------------------------------------
__global__ __launch_bounds__(256) void gather_kernel(
    const float* __restrict__ pc, const float* __restrict__ outC,
    const int* __restrict__ gidx, float* __restrict__ X0,
    float* __restrict__ mpart)
{
    float a[9] = {0, 0, 0, 0, 0, 0, 0, 0, 0};
    for (int p = blockIdx.x * 256 + threadIdx.x; p < PTOT; p += GATH_BLOCKS * 256) {
        int bk = p >> 6;
        int b = bk >> 10;
        int k = bk & (KREG - 1);
        int idx = gidx[p];
        const float* px = pc + (size_t)b * 3 * NPTS;
        float x = px[idx]            - outC[(size_t)b * 3 * KREG + k];
        float y = px[NPTS + idx]     - outC[(size_t)b * 3 * KREG + KREG + k];
        float z = px[2 * NPTS + idx] - outC[(size_t)b * 3 * KREG + 2 * KREG + k];
        X0[p] = x; X0[PTOT + p] = y; X0[2 * PTOT + p] = z;
        a[0] += x;     a[1] += y;     a[2] += z;
        a[3] += x * x; a[4] += y * y; a[5] += z * z;
        a[6] += x * y; a[7] += x * z; a[8] += y * z;
    }
    __shared__ float red[4][9];
    int wv = threadIdx.x >> 6;
    #pragma unroll
    for (int q = 0; q < 9; ++q) {
        float v = a[q];
        #pragma unroll
        for (int s = 32; s > 0; s >>= 1) v += __shfl_xor(v, s, 64);
        if ((threadIdx.x & 63) == 0) red[wv][q] = v;
    }
    __syncthreads();
    if (threadIdx.x < 9) {
        mpart[blockIdx.x * 9 + threadIdx.x] =
            red[0][threadIdx.x] + red[1][threadIdx.x] +
            red[2][threadIdx.x] + red[3][threadIdx.x];
    }
}

// ---------------------------------------------------------------------------
// BN1 params analytically from moments: y1 = W1 x + b1 is linear in x.
// ---------------------------------------------------------------------------
__global__ void bn1_finalize(
    const float* __restrict__ mpart, const float* __restrict__ w1,
    const float* __restrict__ b1, const float* __restrict__ g1,
    const float* __restrict__ be1, float* __restrict__ sc1,
    float* __restrict__ sh1)
{
    __shared__ double M[9];
    int t = threadIdx.x;
    if (t < 9) {
        double s = 0;
        for (int i = 0; i < GATH_BLOCKS; ++i) s += (double)mpart[i * 9 + t];
        M[t] = s / (double)PTOT;
    }
    __syncthreads();
    if (t < 64) {
        double mux = M[0], muy = M[1], muz = M[2];
        double xx = M[3], yy = M[4], zz = M[5], xy = M[6], xz = M[7], yz = M[8];
        double wx = w1[t * 3], wy = w1[t * 3 + 1], wz = w1[t * 3 + 2], bb = b1[t];
        double wmu = wx * mux + wy * muy + wz * muz;
        double mean = wmu + bb;
        double ey2 = wx * wx * xx + wy * wy * yy + wz * wz * zz
                   + 2.0 * (wx * wy * xy + wx * wz * xz + wy * wz * yz)
                   + 2.0 * bb * wmu + bb * bb;
        double var = ey2 - mean * mean;
        double scale = (double)g1[t] / sqrt(var + 1e-5);
        sc1[t] = (float)scale;
        sh1[t] = (float)((double)be1[t] - mean * scale);
    }
}

// ---------------------------------------------------------------------------
// Transpose small weight matrices so conv loops read contiguous (-> s_load).
// ---------------------------------------------------------------------------
__global__ __launch_bounds__(256) void prep_kernel(
    const float* __restrict__ w2, const float* __restrict__ w3,
    float* __restrict__ w2t, float* __restrict__ w3t)
{
    int t = blockIdx.x * 256 + threadIdx.x;
    if (t < 4096) w2t[(t & 63) * 64 + (t >> 6)] = w2[t];
    if (t < 8192) w3t[(t & 63) * 128 + (t >> 6)] = w3[t];
}

// ---------------------------------------------------------------------------
// Pass A: conv1+BN1+ReLU -> conv2, accumulate per-channel sum/sumsq of y2.
// 128 threads/block, 1 position/thread. Activations in LDS columns.
// ---------------------------------------------------------------------------
__global__ __launch_bounds__(128) void conv12_stats_kernel(
    const float* __restrict__ X0,
    const float* __restrict__ w1, const float* __restrict__ b1,
    const float* __restrict__ sc1, const float* __restrict__ sh1,
    const float* __restrict__ w2t, const float* __restrict__ b2,
    float* __restrict__ sum2, float* __restrict__ sq2)
{
    __shared__ float xbuf[64 * 128];
    __shared__ float trans[2][8][65];
    const int t = threadIdx.x;
    const int p = blockIdx.x * 128 + t;

    float x = X0[p], y = X0[PTOT + p], z = X0[2 * PTOT + p];
    #pragma unroll
    for (int o = 0; o < 64; ++o) {
        float v = b1[o];
        v = fmaf(w1[o * 3 + 2], z, v);
        v = fmaf(w1[o * 3 + 1], y, v);
        v = fmaf(w1[o * 3 + 0], x, v);
        v = fmaf(v, sc1[o], sh1[o]);
        xbuf[o * 128 + t] = fmaxf(v, 0.0f);
    }
    float acc[64];
    #pragma unroll
    for (int o = 0; o < 64; ++o) acc[o] = b2[o];
    for (int c = 0; c < 64; ++c) {
        float xv = xbuf[c * 128 + t];
        #pragma unroll
        for (int o = 0; o < 64; ++o) acc[o] = fmaf(w2t[c * 64 + o], xv, acc[o]);
    }
    const int wv = t >> 6, lane = t & 63;
    const int gw = blockIdx.x * 2 + wv;
    #pragma unroll
    for (int ch = 0; ch < 8; ++ch) {
        __syncthreads();
        #pragma unroll
        for (int o = 0; o < 8; ++o) trans[wv][o][lane] = acc[ch * 8 + o];
        __syncthreads();
        int row = lane >> 3, seg = lane & 7;
        float s = 0.f, q = 0.f;
        #pragma unroll
        for (int j = 0; j < 8; ++j) {
            float v = trans[wv][row][seg * 8 + j];
            s += v; q = fmaf(v, v, q);
        }
        s += __shfl_xor(s, 1, 64); q += __shfl_xor(q, 1, 64);
        s += __shfl_xor(s, 2, 64); q += __shfl_xor(q, 2, 64);
        s += __shfl_xor(s, 4, 64); q += __shfl_xor(q, 4, 64);
        if (seg == 0) {
            int o = ch * 8 + row;
            sum2[(size_t)o * NWAVE + gw] = s;
            sq2[(size_t)o * NWAVE + gw] = q;
        }
    }
}

// ---------------------------------------------------------------------------
// Generic BN finalize: per-channel block sums wave partials (f64), emits
// scale/shift.
// ---------------------------------------------------------------------------
__global__ __launch_bounds__(256) void bn_finalize_kernel(
    const float* __restrict__ sumb, const float* __restrict__ sqb,
    const float* __restrict__ g, const float* __restrict__ be,
    float* __restrict__ sc, float* __restrict__ sh)
{
    int o = blockIdx.x, t = threadIdx.x;
    double s = 0, q = 0;
    for (int i = t; i < NWAVE; i += 256) {
        s += (double)sumb[(size_t)o * NWAVE + i];
        q += (double)sqb[(size_t)o * NWAVE + i];
    }
    #pragma unroll
    for (int m = 32; m > 0; m >>= 1) {
        s += __shfl_xor(s, m, 64);
        q += __shfl_xor(q, m, 64);
    }
    __shared__ double rs[4], rq[4];
    if ((t & 63) == 0) { rs[t >> 6] = s; rq[t >> 6] = q; }
    __syncthreads();
    if (t == 0) {
        s = rs[0] + rs[1] + rs[2] + rs[3];
        q = rq[0] + rq[1] + rq[2] + rq[3];
        double mean = s / (double)PTOT;
        double var = q / (double)PTOT - mean * mean;
        double scale = (double)g[o] / sqrt(var + 1e-5);
        sc[o] = (float)scale;
        sh[o] = (float)((double)be[o] - mean * scale);
    }
}

// ---------------------------------------------------------------------------
// Pass B: recompute conv1->conv2 (BN params now known), conv3; emit per-(bk,o)
// max/min of y3 plus per-channel sum/sumsq partials. y3 never stored.
// ---------------------------------------------------------------------------
__global__ __launch_bounds__(128) void conv123_kernel(
    const float* __restrict__ X0,
    const float* __restrict__ w1, const float* __restrict__ b1,
    const float* __restrict__ sc1, const float* __restrict__ sh1,
    const float* __restrict__ w2t, const float* __restrict__ b2,
    const float* __restrict__ sc2, const float* __restrict__ sh2,
    const float* __restrict__ w3t, const float* __restrict__ b3,
    float* __restrict__ y3max, float* __restrict__ y3min,
    float* __restrict__ sum3, float* __restrict__ sq3)
{
    __shared__ float xbuf[64 * 128];
    __shared__ float trans[2][8][65];
    const int t = threadIdx.x;
    const int p = blockIdx.x * 128 + t;

    float x = X0[p], y = X0[PTOT + p], z = X0[2 * PTOT + p];
    #pragma unroll
    for (int o = 0; o < 64; ++o) {
        float v = b1[o];
        v = fmaf(w1[o * 3 + 2], z, v);
        v = fmaf(w1[o * 3 + 1], y, v);
        v = fmaf(w1[o * 3 + 0], x, v);
        v = fmaf(v, sc1[o], sh1[o]);
        xbuf[o * 128 + t] = fmaxf(v, 0.0f);
    }
    float acc2[64];
    #pragma unroll
    for (int o = 0; o < 64; ++o) acc2[o] = b2[o];
    for (int c = 0; c < 64; ++c) {
        float xv = xbuf[c * 128 + t];
        #pragma unroll
        for (int o = 0; o < 64; ++o) acc2[o] = fmaf(w2t[c * 64 + o], xv, acc2[o]);
    }
    #pragma unroll
    for (int o = 0; o < 64; ++o) {
        xbuf[o * 128 + t] = fmaxf(fmaf(acc2[o], sc2[o], sh2[o]), 0.0f);
    }
    float acc3[128];
    #pragma unroll
    for (int o = 0; o < 128; ++o) acc3[o] = b3[o];
    for (int c = 0; c < 64; ++c) {
        float xv = xbuf[c * 128 + t];
        #pragma unroll
        for (int o = 0; o < 128; ++o) acc3[o] = fmaf(w3t[c * 128 + o], xv, acc3[o]);
    }
    const int wv = t >> 6, lane = t & 63;
    const int gw = blockIdx.x * 2 + wv;   // == bk (group) index
    #pragma unroll
    for (int ch = 0; ch < 16; ++ch) {
        __syncthreads();
        #pragma unroll
        for (int o = 0; o < 8; ++o) trans[wv][o][lane] = acc3[ch * 8 + o];
        __syncthreads();
        int row = lane >> 3, seg = lane & 7;
        float s = 0.f, q = 0.f, mx = -1e30f, mn = 1e30f;
        #pragma unroll
        for (int j = 0; j < 8; ++j) {
            float v = trans[wv][row][seg * 8 + j];
            s += v; q = fmaf(v, v, q);
            mx = fmaxf(mx, v); mn = fminf(mn, v);
        }
        s += __shfl_xor(s, 1, 64); q += __shfl_xor(q, 1, 64);
        mx = fmaxf(mx, __shfl_xor(mx, 1, 64)); mn = fminf(mn, __shfl_xor(mn, 1, 64));
        s += __shfl_xor(s, 2, 64); q += __shfl_xor(q, 2, 64);
        mx = fmaxf(mx, __shfl_xor(mx, 2, 64)); mn = fminf(mn, __shfl_xor(mn, 2, 64));
        s += __shfl_xor(s, 4, 64); q += __shfl_xor(q, 4, 64);
        mx = fmaxf(mx, __shfl_xor(mx, 4, 64)); mn = fminf(mn, __shfl_xor(mn, 4, 64));
        if (seg == 0) {
            int o = ch * 8 + row;
            y3max[(size_t)gw * 128 + o] = mx;
            y3min[(size_t)gw * 128 + o] = mn;
            sum3[(size_t)o * NWAVE + gw] = s;
            sq3[(size_t)o * NWAVE + gw] = q;
        }
    }
}

// ---------------------------------------------------------------------------
// Final: feats[b,o,k] = relu(scale3*extreme + shift3), transposed via LDS.
// max over samples commutes with the monotone BN+ReLU (min if scale<0).
// ---------------------------------------------------------------------------
__global__ __launch_bounds__(256) void feats_kernel(
    const float* __restrict__ y3max, const float* __restrict__ y3min,
    const float* __restrict__ sc3, const float* __restrict__ sh3,
    float* __restrict__ feats)
{
    __shared__ float tile[64][129];
    int blk = blockIdx.x;          // b*16 + kt
    int b = blk >> 4, kt = blk & 15;
    int t = threadIdx.x;
    size_t bk0 = (size_t)(b * KREG + kt * 64);
    #pragma unroll
    for (int i = 0; i < 32; ++i) {
        int idx = i * 256 + t;
        int o = idx & 127, kk = idx >> 7;
        float a = sc3[o];
        float v = (a >= 0.f) ? y3max[(bk0 + kk) * 128 + o]
                             : y3min[(bk0 + kk) * 128 + o];
        tile[kk][o] = fmaxf(fmaf(v, a, sh3[o]), 0.0f);
    }
    __syncthreads();
    #pragma unroll
    for (int i = 0; i < 32; ++i) {
        int idx = i * 256 + t;
        int kk = idx & 63, o = idx >> 6;
        feats[(size_t)b * 128 * KREG + (size_t)o * KREG + kt * 64 + kk] = tile[kk][o];
    }
}

// ---------------------------------------------------------------------------
extern "C" void kernel_launch(void* const* d_in, const int* in_sizes, int n_in,
                              void* d_out, int out_size, void* d_ws, size_t ws_size,
                              hipStream_t stream)
{
    const float* pc  = (const float*)d_in[0];
    const float* w1  = (const float*)d_in[1];
    const float* b1  = (const float*)d_in[2];
    const float* g1  = (const float*)d_in[3];
    const float* be1 = (const float*)d_in[4];
    const float* w2  = (const float*)d_in[5];
    const float* b2  = (const float*)d_in[6];
    const float* g2  = (const float*)d_in[7];
    const float* be2 = (const float*)d_in[8];
    const float* w3  = (const float*)d_in[9];
    const float* b3  = (const float*)d_in[10];
    const float* g3  = (const float*)d_in[11];
    const float* be3 = (const float*)d_in[12];

    float* outC  = (float*)d_out;                      // (16,3,1024)
    float* feats = (float*)d_out + NB * 3 * KREG;      // (16,128,1024)

    const size_t MB = 1024 * 1024;
    char* ws = (char*)d_ws;
    int*   gidx  = (int*)ws;                           // 4 MB
    float* X0    = (float*)(ws + 4 * MB);              // 12 MB (3 x P)
    float* mpart = (float*)(ws + 16 * MB);             // 9216 B
    float* sc1   = (float*)(ws + 16 * MB + 16 * 1024);
    float* sh1   = (float*)(ws + 16 * MB + 17 * 1024);
    float* sc2   = (float*)(ws + 16 * MB + 18 * 1024);
    float* sh2   = (float*)(ws + 16 * MB + 19 * 1024);
    float* sc3   = (float*)(ws + 16 * MB + 20 * 1024);
    float* sh3   = (float*)(ws + 16 * MB + 21 * 1024);
    float* w2t   = (float*)(ws + 16 * MB + 32 * 1024); // 16 KB
    float* w3t   = (float*)(ws + 16 * MB + 64 * 1024); // 32 KB
    float* sum2  = (float*)(ws + 17 * MB);             // 4 MB
    float* sq2   = (float*)(ws + 21 * MB);             // 4 MB
    float* sum3  = (float*)(ws + 25 * MB);             // 8 MB
    float* sq3   = (float*)(ws + 33 * MB);             // 8 MB
    float* y3max = (float*)(ws + 41 * MB);             // 8 MB
    float* y3min = (float*)(ws + 49 * MB);             // 8 MB

    fps_kernel<<<NB, 256, 0, stream>>>(pc, outC);
    ballquery_kernel<<<(NB * KREG) / 4, 256, 0, stream>>>(pc, outC, gidx);
    gather_kernel<<<GATH_BLOCKS, 256, 0, stream>>>(pc, outC, gidx, X0, mpart);
    bn1_finalize<<<1, 64, 0, stream>>>(mpart, w1, b1, g1, be1, sc1, sh1);
    prep_kernel<<<32, 256, 0, stream>>>(w2, w3, w2t, w3t);
    conv12_stats_kernel<<<PTOT / 128, 128, 0, stream>>>(
        X0, w1, b1, sc1, sh1, w2t, b2, sum2, sq2);
    bn_finalize_kernel<<<64, 256, 0, stream>>>(sum2, sq2, g2, be2, sc2, sh2);
    conv123_kernel<<<PTOT / 128, 128, 0, stream>>>(
        X0, w1, b1, sc1, sh1, w2t, b2, sc2, sh2, w3t, b3,
        y3max, y3min, sum3, sq3);
    bn_finalize_kernel<<<128, 256, 0, stream>>>(sum3, sq3, g3, be3, sc3, sh3);
    feats_kernel<<<NB * (KREG / 64), 256, 0, stream>>>(y3max, y3min, sc3, sh3, feats);
}